// Round 5
// baseline (315.799 us; speedup 1.0000x reference)
//
#include <hip/hip_runtime.h>
#include <hip/hip_bf16.h>

#define N_NODES 8192
#define D_FEAT 128

typedef __bf16 bf16x8 __attribute__((ext_vector_type(8)));
typedef float f32x4 __attribute__((ext_vector_type(4)));

// ---- cold path: on-the-fly LSH band-collision check (never taken for the
// given Gaussian inputs: max off-diag cosine ~0.49 << 0.75). noinline keeps
// it out of the hot kernel's register/instruction budget.
__device__ __attribute__((noinline)) bool lsh_collide(
    const float* __restrict__ z, const float* __restrict__ H, int i, int j) {
  for (int b = 0; b < 64; ++b) {          // 64 bands x 8 bits
    unsigned ci = 0, cj = 0;
    for (int bit = 0; bit < 8; ++bit) {
      int col = b * 8 + bit;
      float di = 0.f, dj = 0.f;
      for (int k = 0; k < D_FEAT; ++k) {
        float h = H[(size_t)k * 512 + col];
        di += z[(size_t)i * D_FEAT + k] * h;
        dj += z[(size_t)j * D_FEAT + k] * h;
      }
      if (di > 0.f) ci |= (1u << bit);
      if (dj > 0.f) cj |= (1u << bit);
    }
    if (ci == cj) return true;
  }
  return false;
}

__device__ __forceinline__ unsigned pack_bf16x2(float x, float y) {
  __hip_bfloat16 bx = __float2bfloat16(x), by = __float2bfloat16(y);
  return (unsigned)(*(unsigned short*)&bx) |
         ((unsigned)(*(unsigned short*)&by) << 16);
}

// Fused kernel, 64x128 tile, 48 KB LDS -> 3 blocks/CU for phase mixing.
// Single barrier (post-MFMA); epilogue+stores are wave-local and slab-
// pipelined so HBM stores spread across the block lifetime.
__global__ __launch_bounds__(256, 3) void sim_kernel(const float* __restrict__ z,
                                                     const float* __restrict__ H,
                                                     float* __restrict__ out) {
  __shared__ __align__(16) unsigned char smem_raw[49152];
  unsigned short (*As)[128] = (unsigned short (*)[128])smem_raw;            // 64 rows, 16 KB
  unsigned short (*Bs)[128] = (unsigned short (*)[128])(smem_raw + 16384);  // 128 rows, 32 KB
  float* fS = (float*)smem_raw;   // 64 rows x 128 cols fp32 = 32 KB alias

  int tid = threadIdx.x;
  int bm = blockIdx.x, bn = blockIdx.y;   // bm: 64-row strip, bn: 128-col strip

  // ---- Phase 0a: A rows (64), 4 threads/row, 4-lane shuffle reduce ----
  {
    int row = tid >> 2, q = tid & 3;
    const float4* src = (const float4*)(z + (size_t)(bm * 64 + row) * D_FEAT + q * 32);
    float4 v[8];
#pragma unroll
    for (int c = 0; c < 8; ++c) v[c] = src[c];
    float ss = 0.f;
#pragma unroll
    for (int c = 0; c < 8; ++c)
      ss += v[c].x * v[c].x + v[c].y * v[c].y + v[c].z * v[c].z + v[c].w * v[c].w;
    ss += __shfl_xor(ss, 1);
    ss += __shfl_xor(ss, 2);
    float inv = rsqrtf(ss);
#pragma unroll
    for (int c = 0; c < 4; ++c) {
      float4 a = v[2 * c], b = v[2 * c + 1];
      uint4 o;
      o.x = pack_bf16x2(a.x * inv, a.y * inv);
      o.y = pack_bf16x2(a.z * inv, a.w * inv);
      o.z = pack_bf16x2(b.x * inv, b.y * inv);
      o.w = pack_bf16x2(b.z * inv, b.w * inv);
      int cg = q * 4 + c;
      ((uint4*)&As[row][0])[cg ^ (row & 15)] = o;
    }
  }
  // ---- Phase 0b: B rows (128), 2 threads/row, pair shuffle reduce ----
  {
    int row = tid >> 1, half = tid & 1;
    const float4* src = (const float4*)(z + (size_t)(bn * 128 + row) * D_FEAT + half * 64);
    float4 v[16];
#pragma unroll
    for (int c = 0; c < 16; ++c) v[c] = src[c];
    float ss = 0.f;
#pragma unroll
    for (int c = 0; c < 16; ++c)
      ss += v[c].x * v[c].x + v[c].y * v[c].y + v[c].z * v[c].z + v[c].w * v[c].w;
    ss += __shfl_xor(ss, 1);
    float inv = rsqrtf(ss);
#pragma unroll
    for (int c = 0; c < 8; ++c) {
      float4 a = v[2 * c], b = v[2 * c + 1];
      uint4 o;
      o.x = pack_bf16x2(a.x * inv, a.y * inv);
      o.y = pack_bf16x2(a.z * inv, a.w * inv);
      o.z = pack_bf16x2(b.x * inv, b.y * inv);
      o.w = pack_bf16x2(b.z * inv, b.w * inv);
      int cg = half * 8 + c;
      ((uint4*)&Bs[row][0])[cg ^ (row & 15)] = o;
    }
  }
  __syncthreads();

  // ---- Phase 1: MFMA. Wave wv -> 32x64 sub-tile; 2x4 tiles of 16x16x32.
  int wv = tid >> 6, lane = tid & 63;
  int wm = (wv >> 1) * 32, wn = (wv & 1) * 64;
  int m16 = lane & 15, g = lane >> 4;

  f32x4 acc[2][4] = {};

#pragma unroll
  for (int kc = 0; kc < 4; ++kc) {
    bf16x8 fa[2], fb[4];
    int chunk = kc * 4 + g;
    int cs = (chunk ^ m16) * 8;       // row bases multiples of 16 -> row&15 == m16
#pragma unroll
    for (int t = 0; t < 2; ++t) fa[t] = *(const bf16x8*)&As[wm + t * 16 + m16][cs];
#pragma unroll
    for (int t = 0; t < 4; ++t) fb[t] = *(const bf16x8*)&Bs[wn + t * 16 + m16][cs];
#pragma unroll
    for (int tm = 0; tm < 2; ++tm)
#pragma unroll
      for (int tn = 0; tn < 4; ++tn)
        acc[tm][tn] = __builtin_amdgcn_mfma_f32_16x16x32_bf16(fa[tm], fb[tn], acc[tm][tn], 0, 0, 0);
  }

  __syncthreads();   // all waves done with As/Bs before fS aliasing; last barrier

  // ---- Phase 2+3: wave-local epilogue + stores, slab-pipelined (no barriers).
  // C/D layout: col=lane&15, row=g*4+r. Wave region: rows [wm,wm+32), cols
  // [wn,wn+64) of fS. Swizzle chunk' = chunk ^ (row&15) at float4 granularity
  // (write: 64 distinct cols per instr -> 2-way bank = free).
#pragma unroll
  for (int tm = 0; tm < 2; ++tm) {
#pragma unroll
    for (int tn = 0; tn < 4; ++tn) {
      int lc = tn * 16 + m16;               // region-local col
      int j = bn * 128 + wn + lc;
      f32x4 c = acc[tm][tn];
#pragma unroll
      for (int r = 0; r < 4; ++r) {
        int row = wm + tm * 16 + g * 4 + r; // tile-local row
        int i = bm * 64 + row;
        float s = c[r];
        float val = 0.0f;
        if (i == j) {
          val = 1.0f;
        } else if (s > 0.75f) {
          if (lsh_collide(z, H, i, j)) val = s;   // cold path
        }
        int cp = ((lc >> 2) ^ (row & 15)) << 2;   // swizzled chunk base
        fS[row * 128 + wn + cp + (lc & 3)] = val;
      }
    }
    // store this 16-row x 64-col slab: 4 x (4 rows of 256B contiguous)
#pragma unroll
    for (int it = 0; it < 4; ++it) {
      int slot = it * 64 + lane;            // 0..255
      int r16 = slot >> 4, chunk = slot & 15;
      int row = wm + tm * 16 + r16;
      f32x4 v = *(const f32x4*)&fS[row * 128 + wn + ((chunk ^ r16) << 2)];
      *(f32x4*)&out[(size_t)(bm * 64 + row) * N_NODES + bn * 128 + wn + chunk * 4] = v;
    }
  }
}

extern "C" void kernel_launch(void* const* d_in, const int* in_sizes, int n_in,
                              void* d_out, int out_size, void* d_ws, size_t ws_size,
                              hipStream_t stream) {
  const float* z = (const float*)d_in[0];   // [8192, 128] fp32
  const float* H = (const float*)d_in[1];   // [128, 512] fp32
  // d_in[2] = edge_index, unused by the reference forward.
  float* out = (float*)d_out;               // [8192, 8192] fp32
  (void)d_ws; (void)ws_size;

  sim_kernel<<<dim3(N_NODES / 64, N_NODES / 128), 256, 0, stream>>>(z, H, out);
}

// Round 6
// 302.853 us; speedup vs baseline: 1.0427x; 1.0427x over previous
//
#include <hip/hip_runtime.h>
#include <hip/hip_bf16.h>
#include <math.h>

#define N_NODES 8192
#define D_FEAT 128

typedef __bf16 bf16x8 __attribute__((ext_vector_type(8)));
typedef float f32x4 __attribute__((ext_vector_type(4)));

// ---- cold path: on-the-fly LSH band-collision check (never taken for the
// given Gaussian inputs: max off-diag cosine ~0.49 << 0.75). noinline keeps
// it out of the hot kernel's register/instruction budget.
__device__ __attribute__((noinline)) bool lsh_collide(
    const float* __restrict__ z, const float* __restrict__ H, int i, int j) {
  for (int b = 0; b < 64; ++b) {          // 64 bands x 8 bits
    unsigned ci = 0, cj = 0;
    for (int bit = 0; bit < 8; ++bit) {
      int col = b * 8 + bit;
      float di = 0.f, dj = 0.f;
      for (int k = 0; k < D_FEAT; ++k) {
        float h = H[(size_t)k * 512 + col];
        di += z[(size_t)i * D_FEAT + k] * h;
        dj += z[(size_t)j * D_FEAT + k] * h;
      }
      if (di > 0.f) ci |= (1u << bit);
      if (dj > 0.f) cj |= (1u << bit);
    }
    if (ci == cj) return true;
  }
  return false;
}

__device__ __forceinline__ unsigned pack_bf16x2(float x, float y) {
  __hip_bfloat16 bx = __float2bfloat16(x), by = __float2bfloat16(y);
  return (unsigned)(*(unsigned short*)&bx) |
         ((unsigned)(*(unsigned short*)&by) << 16);
}

// Fused + SYMMETRIC kernel. R4's verified 128x128 structure, but only the
// 2080 lower-triangle tiles (bm >= bn) are computed; off-diagonal tiles are
// stored twice: normal tile via swizzled-LDS coalesced dwordx4, transposed
// tile register-direct (C-layout regs = 4 consecutive rows @ one col = one
// contiguous float4 of the transposed tile), issued inside the epilogue so
// HBM writes spread across the block lifetime.
__global__ __launch_bounds__(256, 2) void sim_kernel(const float* __restrict__ z,
                                                     const float* __restrict__ H,
                                                     float* __restrict__ out) {
  __shared__ __align__(16) unsigned char smem_raw[65536];
  unsigned short (*As)[128] = (unsigned short (*)[128])smem_raw;            // 32 KB
  unsigned short (*Bs)[128] = (unsigned short (*)[128])(smem_raw + 32768);  // 32 KB
  float* fS = (float*)smem_raw;                                             // 64 KB alias

  int tid = threadIdx.x;

  // triangular decode: block t -> (bm, bn), bm >= bn
  int t = (int)blockIdx.x;
  int bm = (int)((sqrtf(8.f * (float)t + 1.f) - 1.f) * 0.5f);
  while ((bm + 1) * (bm + 2) / 2 <= t) ++bm;
  while (bm * (bm + 1) / 2 > t) --bm;
  int bn = t - bm * (bm + 1) / 2;

  // ---- Phase 0: fused normalize (R4-verified). 2 threads/row; pass 0 = A
  // rows (bm), pass 1 = B rows (bn). Pair-shuffle row reduce; swizzled 16B
  // LDS writes.
  {
    int row = tid >> 1, half = tid & 1;
#pragma unroll
    for (int pass = 0; pass < 2; ++pass) {
      int gr = (pass ? bn : bm) * 128 + row;
      const float4* src = (const float4*)(z + (size_t)gr * D_FEAT + half * 64);
      float4 v[16];
#pragma unroll
      for (int c = 0; c < 16; ++c) v[c] = src[c];
      float ss = 0.f;
#pragma unroll
      for (int c = 0; c < 16; ++c)
        ss += v[c].x * v[c].x + v[c].y * v[c].y + v[c].z * v[c].z + v[c].w * v[c].w;
      ss += __shfl_xor(ss, 1);            // combine the two half-rows
      float inv = rsqrtf(ss);
      unsigned short (*T)[128] = pass ? Bs : As;
#pragma unroll
      for (int c = 0; c < 8; ++c) {
        float4 a = v[2 * c], b = v[2 * c + 1];
        uint4 o;
        o.x = pack_bf16x2(a.x * inv, a.y * inv);
        o.y = pack_bf16x2(a.z * inv, a.w * inv);
        o.z = pack_bf16x2(b.x * inv, b.y * inv);
        o.w = pack_bf16x2(b.z * inv, b.w * inv);
        int cg = half * 8 + c;            // chunk index within the row
        ((uint4*)&T[row][0])[cg ^ (row & 15)] = o;
      }
    }
  }
  __syncthreads();

  // ---- Phase 1: MFMA (R2/R4-verified). Wave -> 64x64; 4x4 x 16x16x32.
  int wv = tid >> 6, lane = tid & 63;
  int wm = (wv >> 1) * 64, wn = (wv & 1) * 64;
  int m16 = lane & 15, g = lane >> 4;

  f32x4 acc[4][4] = {};

#pragma unroll
  for (int kc = 0; kc < 4; ++kc) {
    bf16x8 fa[4], fb[4];
    int chunk = kc * 4 + g;
    int cs = (chunk ^ m16) * 8;           // row bases multiples of 16 -> row&15 == m16
#pragma unroll
    for (int tt = 0; tt < 4; ++tt) {
      fa[tt] = *(const bf16x8*)&As[wm + tt * 16 + m16][cs];
      fb[tt] = *(const bf16x8*)&Bs[wn + tt * 16 + m16][cs];
    }
#pragma unroll
    for (int tm = 0; tm < 4; ++tm)
#pragma unroll
      for (int tn = 0; tn < 4; ++tn)
        acc[tm][tn] = __builtin_amdgcn_mfma_f32_16x16x32_bf16(fa[tm], fb[tn], acc[tm][tn], 0, 0, 0);
  }

  __syncthreads();   // all waves done with As/Bs before fS aliasing

  // ---- Phase 2: epilogue in C-layout (col=lane&15, row=g*4+r).
  // Transposed tile stored register-direct here (off-diag only); normal
  // tile staged into swizzled fS for phase 3.
  bool offdiag = (bm != bn);
#pragma unroll
  for (int tm = 0; tm < 4; ++tm) {
#pragma unroll
    for (int tn = 0; tn < 4; ++tn) {
      int col = wn + tn * 16 + m16;       // tile-local col
      int j = bn * 128 + col;
      int rowb = wm + tm * 16 + g * 4;    // tile-local row base
      int ib = bm * 128 + rowb;
      f32x4 c = acc[tm][tn];
      f32x4 vt;
#pragma unroll
      for (int r = 0; r < 4; ++r) {
        int i = ib + r;
        float s = c[r];
        float val = 0.0f;
        if (i == j) {
          val = 1.0f;
        } else if (s > 0.75f) {
          if (lsh_collide(z, H, i, j)) val = s;   // cold path
        }
        vt[r] = val;
        fS[(rowb + r) * 128 + ((((col >> 2) ^ ((rowb + r) & 31)) << 2) | (col & 3))] = val;
      }
      if (offdiag)   // transposed tile: row j, cols ib..ib+3 (16B aligned)
        *(f32x4*)&out[(size_t)j * N_NODES + ib] = vt;
    }
  }
  __syncthreads();

  // ---- Phase 3: normal tile, fully coalesced dwordx4 stores (512B runs).
#pragma unroll
  for (int r = 0; r < 16; ++r) {
    int slot = tid + 256 * r;             // 0..4095 float4 slots
    int row = slot >> 5, chunk = slot & 31;
    float4 v = *(const float4*)&fS[row * 128 + ((chunk ^ (row & 31)) << 2)];
    *(float4*)&out[(size_t)(bm * 128 + row) * N_NODES + bn * 128 + chunk * 4] = v;
  }
}

extern "C" void kernel_launch(void* const* d_in, const int* in_sizes, int n_in,
                              void* d_out, int out_size, void* d_ws, size_t ws_size,
                              hipStream_t stream) {
  const float* z = (const float*)d_in[0];   // [8192, 128] fp32
  const float* H = (const float*)d_in[1];   // [128, 512] fp32
  // d_in[2] = edge_index, unused by the reference forward.
  float* out = (float*)d_out;               // [8192, 8192] fp32
  (void)d_ws; (void)ws_size;

  sim_kernel<<<64 * 65 / 2, 256, 0, stream>>>(z, H, out);
}

// Round 8
// 278.277 us; speedup vs baseline: 1.1348x; 1.0883x over previous
//
#include <hip/hip_runtime.h>
#include <hip/hip_bf16.h>

#define N_NODES 8192
#define D_FEAT 128

typedef __bf16 bf16x8 __attribute__((ext_vector_type(8)));
typedef float f32x4 __attribute__((ext_vector_type(4)));

// Barrier that waits ONLY on LDS ops (lgkmcnt(0)) — does NOT drain vmcnt,
// so global stores issued before it stay in flight across the barrier.
// Inline asm with "memory" clobber = real compiler fence (the R7 builtins
// were not, and the compiler reordered LDS ops across the barrier).
__device__ __forceinline__ void lgkm_barrier() {
  asm volatile("s_waitcnt lgkmcnt(0)\n\ts_barrier" ::: "memory");
}
// Wave-local LDS write->read ordering point (no cross-wave barrier needed).
__device__ __forceinline__ void lgkm_fence() {
  asm volatile("s_waitcnt lgkmcnt(0)" ::: "memory");
}

// ---- cold path: on-the-fly LSH band-collision check (never taken for the
// given Gaussian inputs: max off-diag cosine ~0.49 << 0.75).
__device__ __attribute__((noinline)) bool lsh_collide(
    const float* __restrict__ z, const float* __restrict__ H, int i, int j) {
  for (int b = 0; b < 64; ++b) {          // 64 bands x 8 bits
    unsigned ci = 0, cj = 0;
    for (int bit = 0; bit < 8; ++bit) {
      int col = b * 8 + bit;
      float di = 0.f, dj = 0.f;
      for (int k = 0; k < D_FEAT; ++k) {
        float h = H[(size_t)k * 512 + col];
        di += z[(size_t)i * D_FEAT + k] * h;
        dj += z[(size_t)j * D_FEAT + k] * h;
      }
      if (di > 0.f) ci |= (1u << bit);
      if (dj > 0.f) cj |= (1u << bit);
    }
    if (ci == cj) return true;
  }
  return false;
}

__device__ __forceinline__ unsigned pack_bf16x2(float x, float y) {
  __hip_bfloat16 bx = __float2bfloat16(x), by = __float2bfloat16(y);
  return (unsigned)(*(unsigned short*)&bx) |
         ((unsigned)(*(unsigned short*)&by) << 16);
}

// Normalize 128 z-rows of block `blk` into bf16 tile T (XOR-swizzled 16B
// chunks). 2 threads/row, pair-shuffle reduce. (R4-verified.)
__device__ __forceinline__ void stage_tile(const float* __restrict__ z, int blk,
                                           unsigned short (*T)[128], int tid) {
  int row = tid >> 1, half = tid & 1;
  const float4* src = (const float4*)(z + (size_t)(blk * 128 + row) * D_FEAT + half * 64);
  float4 v[16];
#pragma unroll
  for (int c = 0; c < 16; ++c) v[c] = src[c];
  float ss = 0.f;
#pragma unroll
  for (int c = 0; c < 16; ++c)
    ss += v[c].x * v[c].x + v[c].y * v[c].y + v[c].z * v[c].z + v[c].w * v[c].w;
  ss += __shfl_xor(ss, 1);
  float inv = rsqrtf(ss);
#pragma unroll
  for (int c = 0; c < 8; ++c) {
    float4 a = v[2 * c], b = v[2 * c + 1];
    uint4 o;
    o.x = pack_bf16x2(a.x * inv, a.y * inv);
    o.y = pack_bf16x2(a.z * inv, a.w * inv);
    o.z = pack_bf16x2(b.x * inv, b.y * inv);
    o.w = pack_bf16x2(b.z * inv, b.w * inv);
    ((uint4*)&T[row][0])[(half * 8 + c) ^ (row & 15)] = o;
  }
}

// Persistent-block fused kernel. 512 blocks (2/CU); block b owns bn = b&63
// (Bs staged ONCE, resident), loops 8 bm-tiles. Epilogue stages per-wave
// 4 KB slabs (aliasing the As region only) and stores them wave-locally;
// ALL barriers are lgkm-only -> tile-t stores stay in flight across
// tile-(t+1) staging + MFMA (removes the vmcnt(0) barrier drain that
// capped R4 at ~2x the write roofline).
__global__ __launch_bounds__(256, 2) void sim_kernel(const float* __restrict__ z,
                                                     const float* __restrict__ H,
                                                     float* __restrict__ out) {
  __shared__ __align__(16) unsigned char smem_raw[65536];
  unsigned short (*As)[128] = (unsigned short (*)[128])smem_raw;            // 32 KB (aliased by fS slabs)
  unsigned short (*Bs)[128] = (unsigned short (*)[128])(smem_raw + 32768);  // 32 KB persistent
  float* fS = (float*)smem_raw;   // per-wave slabs: wv*2048 + parity*1024 floats

  int tid = threadIdx.x;
  int b = (int)blockIdx.x;
  int bn = b & 63;
  int bm0 = b >> 6;               // 0..7

  int wv = tid >> 6, lane = tid & 63;
  int wm = (wv >> 1) * 64, wn = (wv & 1) * 64;
  int m16 = lane & 15, g = lane >> 4;
  float* fSw = fS + wv * 2048;

  // ---- stage Bs once (resident for all 8 tiles) ----
  stage_tile(z, bn, Bs, tid);

  for (int t = 0; t < 8; ++t) {
    int bm = bm0 * 8 + t;

    // B4: all waves' slab ds_reads from tile t-1 are done -> safe to
    // overwrite the As/slab region. Global stores stay in flight.
    lgkm_barrier();
    stage_tile(z, bm, As, tid);
    lgkm_barrier();   // B1: staging visible to all waves

    // ---- MFMA: wave -> 64x64 quadrant, 4x4 tiles of 16x16x32, K=128 ----
    f32x4 acc[4][4] = {};
#pragma unroll
    for (int kc = 0; kc < 4; ++kc) {
      bf16x8 fa[4], fb[4];
      int chunk = kc * 4 + g;
      int cs = (chunk ^ m16) * 8;   // row bases multiples of 16 -> row&15 == m16
#pragma unroll
      for (int tt = 0; tt < 4; ++tt) {
        fa[tt] = *(const bf16x8*)&As[wm + tt * 16 + m16][cs];
        fb[tt] = *(const bf16x8*)&Bs[wn + tt * 16 + m16][cs];
      }
#pragma unroll
      for (int tm = 0; tm < 4; ++tm)
#pragma unroll
        for (int tn = 0; tn < 4; ++tn)
          acc[tm][tn] = __builtin_amdgcn_mfma_f32_16x16x32_bf16(fa[tm], fb[tn], acc[tm][tn], 0, 0, 0);
    }

    lgkm_barrier();   // B2: all waves' As frag reads done before slab writes

    // ---- epilogue + wave-local slab stores (no cross-wave sync needed) ----
    // C/D layout: col=lane&15, row=g*4+r. Slab = 16 rows x 64 cols fp32,
    // swizzle chunk' = (col>>2) ^ rowInSlab.
#pragma unroll
    for (int tm = 0; tm < 4; ++tm) {
      float* slab = fSw + (tm & 1) * 1024;
#pragma unroll
      for (int tn = 0; tn < 4; ++tn) {
        int colq = tn * 16 + m16;          // quadrant-local col 0..63
        int j = bn * 128 + wn + colq;
        f32x4 c = acc[tm][tn];
#pragma unroll
        for (int r = 0; r < 4; ++r) {
          int rs = g * 4 + r;              // slab row 0..15
          int i = bm * 128 + wm + tm * 16 + rs;
          float s = c[r];
          float val = 0.0f;
          if (i == j) {
            val = 1.0f;
          } else if (s > 0.75f) {
            if (lsh_collide(z, H, i, j)) val = s;   // cold path
          }
          slab[rs * 64 + (((colq >> 2) ^ rs) << 2) + (colq & 3)] = val;
        }
      }
      lgkm_fence();   // slab writes complete before cross-lane readback
      // store slab: 4 instrs, each 4 rows x 256B contiguous segments
#pragma unroll
      for (int it = 0; it < 4; ++it) {
        int rs = it * 4 + g;
        f32x4 v = *(const f32x4*)&slab[rs * 64 + ((m16 ^ rs) << 2)];
        int grow = bm * 128 + wm + tm * 16 + rs;
        *(f32x4*)&out[(size_t)grow * N_NODES + bn * 128 + wn + m16 * 4] = v;
      }
    }
  }
}

extern "C" void kernel_launch(void* const* d_in, const int* in_sizes, int n_in,
                              void* d_out, int out_size, void* d_ws, size_t ws_size,
                              hipStream_t stream) {
  const float* z = (const float*)d_in[0];   // [8192, 128] fp32
  const float* H = (const float*)d_in[1];   // [128, 512] fp32
  // d_in[2] = edge_index, unused by the reference forward.
  float* out = (float*)d_out;               // [8192, 8192] fp32
  (void)d_ws; (void)ws_size;

  sim_kernel<<<512, 256, 0, stream>>>(z, H, out);
}